// Round 4
// baseline (248.730 us; speedup 1.0000x reference)
//
#include <hip/hip_runtime.h>

#define NT 256

// v6: dual-column ILP. Each block processes 4 rows = 2 independent complex FFTs
// (P = rows 4b,4b+1; Q = rows 4b+2,4b+3) interleaved in registers, so every
// stall (LDS round-trip, FMA chain, twiddle chain) has a sibling stream to
// issue under. Barriers/sincos/H-loads/address math amortize over 2 columns.
//
// LDS: 64 KB exactly (2 blocks/CU). P at float2[0,4096), Q at +4096 -> same
// address registers, Q reached via ds-instruction immediate offset +32768 B.
// XOR swizzle phys(l) = l ^ (((l>>4)&7)<<1) unchanged (conflict-free for all
// four exchange patterns; bit0 untouched -> b128 pairs stay aligned+ordered).
//
// launch_bounds(NT,2): 256-VGPR budget -> no spill (v4 lesson: never starve
// the allocator; spills cost more than occupancy).

template<bool INV>
__device__ __forceinline__ void dft16(float* vr, float* vi) {
    constexpr float C1 = 0.9238795325112867f;   // cos(pi/8)
    constexpr float S1 = 0.3826834323650898f;   // sin(pi/8)
    constexpr float HF = 0.7071067811865476f;
    const float WR[10] = {1.f,  C1,  HF,  S1, 0.f, 0.f, -HF, 0.f, 0.f, -C1};
    const float WI[10] = {0.f, -S1, -HF, -C1, -1.f, 0.f, -HF, 0.f, 0.f,  S1};

    float ar[16], ai[16];
    #pragma unroll
    for (int jl = 0; jl < 4; ++jl) {
        float x0r = vr[jl],      x0i = vi[jl];
        float x1r = vr[jl + 4],  x1i = vi[jl + 4];
        float x2r = vr[jl + 8],  x2i = vi[jl + 8];
        float x3r = vr[jl + 12], x3i = vi[jl + 12];
        float t0r = x0r + x2r, t0i = x0i + x2i;
        float t1r = x0r - x2r, t1i = x0i - x2i;
        float t2r = x1r + x3r, t2i = x1i + x3i;
        float t3r = x1r - x3r, t3i = x1i - x3i;
        ar[jl]     = t0r + t2r;  ai[jl]     = t0i + t2i;
        ar[jl + 8] = t0r - t2r;  ai[jl + 8] = t0i - t2i;
        if (!INV) {
            ar[jl + 4]  = t1r + t3i;  ai[jl + 4]  = t1i - t3r;  // t1 - i*t3
            ar[jl + 12] = t1r - t3i;  ai[jl + 12] = t1i + t3r;  // t1 + i*t3
        } else {
            ar[jl + 4]  = t1r - t3i;  ai[jl + 4]  = t1i + t3r;
            ar[jl + 12] = t1r + t3i;  ai[jl + 12] = t1i - t3r;
        }
    }
    #pragma unroll
    for (int k4 = 1; k4 < 4; ++k4) {
        #pragma unroll
        for (int jl = 1; jl < 4; ++jl) {
            const int e = jl * k4;
            float wr = WR[e];
            float wi = INV ? -WI[e] : WI[e];
            const int id = jl + 4 * k4;
            float xr = ar[id], xi = ai[id];
            ar[id] = xr * wr - xi * wi;
            ai[id] = xr * wi + xi * wr;
        }
    }
    #pragma unroll
    for (int k4 = 0; k4 < 4; ++k4) {
        float x0r = ar[4*k4 + 0], x0i = ai[4*k4 + 0];
        float x1r = ar[4*k4 + 1], x1i = ai[4*k4 + 1];
        float x2r = ar[4*k4 + 2], x2i = ai[4*k4 + 2];
        float x3r = ar[4*k4 + 3], x3i = ai[4*k4 + 3];
        float t0r = x0r + x2r, t0i = x0i + x2i;
        float t1r = x0r - x2r, t1i = x0i - x2i;
        float t2r = x1r + x3r, t2i = x1i + x3i;
        float t3r = x1r - x3r, t3i = x1i - x3i;
        vr[k4]     = t0r + t2r;  vi[k4]     = t0i + t2i;
        vr[k4 + 8] = t0r - t2r;  vi[k4 + 8] = t0i - t2i;
        if (!INV) {
            vr[k4 + 4]  = t1r + t3i;  vi[k4 + 4]  = t1i - t3r;
            vr[k4 + 12] = t1r - t3i;  vi[k4 + 12] = t1i + t3r;
        } else {
            vr[k4 + 4]  = t1r - t3i;  vi[k4 + 4]  = t1i + t3r;
            vr[k4 + 12] = t1r + t3i;  vi[k4 + 12] = t1i - t3r;
        }
    }
}

// Twiddle powers generated ONCE, applied to both columns (P,Q): the serial
// w^2-stepping chains amortize and the two applications interleave for ILP.
__device__ __forceinline__ void apply_tw_dual(float* vrP, float* viP,
                                              float* vrQ, float* viQ,
                                              float wr, float wi) {
    const float w2r = wr * wr - wi * wi;
    const float w2i = 2.0f * wr * wi;
    float aor = wr,  aoi = wi;    // odd powers: w^1, w^3, ...
    float aer = w2r, aei = w2i;   // even powers: w^2, w^4, ...
    #pragma unroll
    for (int e = 1; e < 16; e += 2) {
        { float xr = vrP[e], xi = viP[e];
          vrP[e] = xr * aor - xi * aoi;
          viP[e] = xr * aoi + xi * aor; }
        { float xr = vrQ[e], xi = viQ[e];
          vrQ[e] = xr * aor - xi * aoi;
          viQ[e] = xr * aoi + xi * aor; }
        if (e + 1 < 16) {
            { float xr = vrP[e + 1], xi = viP[e + 1];
              vrP[e + 1] = xr * aer - xi * aei;
              viP[e + 1] = xr * aei + xi * aer; }
            { float xr = vrQ[e + 1], xi = viQ[e + 1];
              vrQ[e + 1] = xr * aer - xi * aei;
              viQ[e + 1] = xr * aei + xi * aer; }
        }
        if (e + 2 < 16) {
            float nr = aor * w2r - aoi * w2i, ni = aor * w2i + aoi * w2r;
            aor = nr; aoi = ni;
            nr = aer * w2r - aei * w2i; ni = aer * w2i + aei * w2r;
            aer = nr; aei = ni;
        }
    }
}

__device__ __forceinline__ void cmul(float& r, float& i, float hr, float hi) {
    float xr = r, xi = i;
    r = xr * hr - xi * hi;
    i = xr * hi + xi * hr;
}

__global__ __launch_bounds__(NT, 2) void spectral_circulant_r16v6(
    const float* __restrict__ x,
    const float* __restrict__ w_real,
    const float* __restrict__ w_imag,
    const float* __restrict__ bias_p,
    float* __restrict__ out)
{
    __shared__ __align__(16) float2 lds[8192];   // 64 KB: P [0,4096), Q [4096,8192)

    const int t   = threadIdx.x;
    const int blk = blockIdx.x;

    float vrP[16], viP[16], vrQ[16], viQ[16];

    // ---- load four rows: P = rowA + i*rowB, Q = rowC + i*rowD ----
    const float* __restrict__ xa = x + (size_t)(4 * blk) * 4096;
    #pragma unroll
    for (int j = 0; j < 16; ++j) {
        const int o = (j << 8) + t;
        vrP[j] = xa[o];
        viP[j] = xa[o + 4096];
        vrQ[j] = xa[o + 8192];
        viQ[j] = xa[o + 12288];
    }

    // ---- stage A: DFT16 over j -> digit a; twiddle W4096^{t*a} ----
    dft16<false>(vrP, viP);
    dft16<false>(vrQ, viQ);
    float sA, cA;
    __sincosf((float)t * -1.5339807878856412e-3f, &sA, &cA);  // -2pi/4096
    apply_tw_dual(vrP, viP, vrQ, viQ, cA, sA);

    // ---- exchange 1 write: l = 256a + t; phys = 256a + tswz (b64 x2) ----
    {
        const int tswz = t ^ ((t >> 3) & 0xE);   // t ^ (((t>>4)&7)<<1)
        #pragma unroll
        for (int a = 0; a < 16; ++a) {
            lds[(a << 8) + tswz]        = make_float2(vrP[a], viP[a]);
            lds[(a << 8) + tswz + 4096] = make_float2(vrQ[a], viQ[a]);
        }
    }
    __syncthreads();

    const int ax = t >> 4;               // upper digit this thread owns from here on
    const int m2 = t & 15;               // lower digit

    // 8 swizzled column bases: phys(256ax + 16q + m2) = swzbase[q&7] + 16q.
    int swzbase[8];
    #pragma unroll
    for (int c = 0; c < 8; ++c)
        swzbase[c] = (ax << 8) + (m2 ^ (c << 1));

    // ---- exchange 1 read: l = 256ax + 16q + m2 (b64 x2) ----
    #pragma unroll
    for (int q = 0; q < 16; ++q) {
        float2 vP = lds[swzbase[q & 7] + (q << 4)];
        float2 vQ = lds[swzbase[q & 7] + (q << 4) + 4096];
        vrP[q] = vP.x; viP[q] = vP.y;
        vrQ[q] = vQ.x; viQ[q] = vQ.y;
    }

    // ---- stage B: DFT16 over q -> digit b; twiddle W256^{m2*b} ----
    dft16<false>(vrP, viP);
    dft16<false>(vrQ, viQ);
    float sB, cB;
    __sincosf((float)m2 * -2.454369260617026e-2f, &sB, &cB);  // -2pi/256
    apply_tw_dual(vrP, viP, vrQ, viQ, cB, sB);

    // ---- exchange 2 write: l = 256ax + 16b + m2 — wave-local (16-lane groups) ----
    #pragma unroll
    for (int b = 0; b < 16; ++b) {
        lds[swzbase[b & 7] + (b << 4)]        = make_float2(vrP[b], viP[b]);
        lds[swzbase[b & 7] + (b << 4) + 4096] = make_float2(vrQ[b], viQ[b]);
    }
    __builtin_amdgcn_wave_barrier();

    // ---- exchange 2 read: 16 contiguous at l0 = 256ax + 16*m2; b128 x2 ----
    const int c2 = (m2 & 7) << 1;
    const float2* __restrict__ pbase = &lds[(ax << 8) + (m2 << 4)];
    #pragma unroll
    for (int m = 0; m < 16; m += 2) {
        float4 vP = *(const float4*)&pbase[m ^ c2];
        float4 vQ = *(const float4*)&pbase[(m ^ c2) + 4096];
        vrP[m] = vP.x;     viP[m] = vP.y;
        vrP[m + 1] = vP.z; viP[m + 1] = vP.w;
        vrQ[m] = vQ.x;     viQ[m] = vQ.y;
        vrQ[m + 1] = vQ.z; viQ[m + 1] = vQ.w;
    }

    // ---- stage C: DFT16 over m -> digit r3; freq k = 256*r3 + 16*m2 + ax ----
    dft16<false>(vrP, viP);
    dft16<false>(vrQ, viQ);

    // ---- pointwise H[k]/N — H loads shared by both columns ----
    {
        const int c = (m2 << 4) | ax;            // in [0,255]
        const float sc = 1.0f / 4096.0f;
        #pragma unroll
        for (int r3 = 0; r3 < 4; ++r3) {         // k < 1024: active
            const int k = (r3 << 8) + c;
            float hr = w_real[k] * sc;
            float hi = w_imag[k] * sc;
            cmul(vrP[r3], viP[r3], hr, hi);
            cmul(vrQ[r3], viQ[r3], hr, hi);
        }
        #pragma unroll
        for (int r3 = 4; r3 < 12; ++r3) {        // truncated band
            vrP[r3] = 0.0f; viP[r3] = 0.0f;
            vrQ[r3] = 0.0f; viQ[r3] = 0.0f;
        }
        {                                        // r3=12: k=3072+c, active iff c>0
            const int idx = 1024 - c;
            const float mm = (c > 0) ? sc : 0.0f;
            float hr = w_real[idx] * mm;
            float hi = -w_imag[idx] * mm;
            cmul(vrP[12], viP[12], hr, hi);
            cmul(vrQ[12], viQ[12], hr, hi);
        }
        #pragma unroll
        for (int r3 = 13; r3 < 16; ++r3) {       // k > 3072: conj mirror
            const int idx = ((16 - r3) << 8) - c;
            float hr = w_real[idx] * sc;
            float hi = -w_imag[idx] * sc;
            cmul(vrP[r3], viP[r3], hr, hi);
            cmul(vrQ[r3], viQ[r3], hr, hi);
        }
    }

    // ================= inverse: exact adjoint, reverse order =================

    // ---- C^H ----
    dft16<true>(vrP, viP);
    dft16<true>(vrQ, viQ);

    // ---- exchange 2 reverse write (b128 x2) ----
    {
        float2* __restrict__ pw = &lds[(ax << 8) + (m2 << 4)];
        #pragma unroll
        for (int m = 0; m < 16; m += 2) {
            *(float4*)&pw[m ^ c2]          = make_float4(vrP[m], viP[m], vrP[m + 1], viP[m + 1]);
            *(float4*)&pw[(m ^ c2) + 4096] = make_float4(vrQ[m], viQ[m], vrQ[m + 1], viQ[m + 1]);
        }
    }
    __builtin_amdgcn_wave_barrier();

    // ---- exchange 2 reverse read (b64 x2) ----
    #pragma unroll
    for (int b = 0; b < 16; ++b) {
        float2 vP = lds[swzbase[b & 7] + (b << 4)];
        float2 vQ = lds[swzbase[b & 7] + (b << 4) + 4096];
        vrP[b] = vP.x; viP[b] = vP.y;
        vrQ[b] = vQ.x; viQ[b] = vQ.y;
    }

    // ---- B^H ----
    apply_tw_dual(vrP, viP, vrQ, viQ, cB, -sB);
    dft16<true>(vrP, viP);
    dft16<true>(vrQ, viQ);

    // ---- exchange 1 reverse write (b64 x2) ----
    #pragma unroll
    for (int q = 0; q < 16; ++q) {
        lds[swzbase[q & 7] + (q << 4)]        = make_float2(vrP[q], viP[q]);
        lds[swzbase[q & 7] + (q << 4) + 4096] = make_float2(vrQ[q], viQ[q]);
    }
    __syncthreads();

    // ---- exchange 1 reverse read (b64 x2) ----
    {
        const int tswz = t ^ ((t >> 3) & 0xE);
        #pragma unroll
        for (int a = 0; a < 16; ++a) {
            float2 vP = lds[(a << 8) + tswz];
            float2 vQ = lds[(a << 8) + tswz + 4096];
            vrP[a] = vP.x; viP[a] = vP.y;
            vrQ[a] = vQ.x; viQ[a] = vQ.y;
        }
    }

    // ---- A^H ----
    apply_tw_dual(vrP, viP, vrQ, viQ, cA, -sA);
    dft16<true>(vrP, viP);
    dft16<true>(vrQ, viQ);

    // ---- store (nontemporal: streamed output) ----
    const float bv = bias_p[0];
    float* __restrict__ oa = out + (size_t)(4 * blk) * 4096;
    #pragma unroll
    for (int j = 0; j < 16; ++j) {
        const int o = (j << 8) + t;
        __builtin_nontemporal_store(vrP[j] + bv, &oa[o]);
        __builtin_nontemporal_store(viP[j] + bv, &oa[o + 4096]);
        __builtin_nontemporal_store(vrQ[j] + bv, &oa[o + 8192]);
        __builtin_nontemporal_store(viQ[j] + bv, &oa[o + 12288]);
    }
}

extern "C" void kernel_launch(void* const* d_in, const int* in_sizes, int n_in,
                              void* d_out, int out_size, void* d_ws, size_t ws_size,
                              hipStream_t stream) {
    (void)in_sizes; (void)n_in; (void)d_ws; (void)ws_size; (void)out_size;
    const float* x      = (const float*)d_in[0];   // (8192, 4096) f32
    const float* w_real = (const float*)d_in[1];   // (2049,) f32
    const float* w_imag = (const float*)d_in[2];   // (2049,) f32
    const float* bias   = (const float*)d_in[3];   // scalar f32
    float* out = (float*)d_out;                    // (8192, 4096) f32

    spectral_circulant_r16v6<<<8192 / 4, NT, 0, stream>>>(x, w_real, w_imag, bias, out);
}

// Round 6
// 243.557 us; speedup vs baseline: 1.0212x; 1.0212x over previous
//
#include <hip/hip_runtime.h>

#define NT 256

// v7: packed-FP32 dual-column. Columns P (rows 4b,4b+1) and Q (rows 4b+2,4b+3)
// ride in one v2f (ext_vector float2) per logical value -> every butterfly /
// twiddle / pointwise op is ONE v_pk_{fma,mul,add}_f32 instead of two scalar
// ops (v6). Halves VALU instruction count vs v6 at identical numerics.
//
// LDS: dual-plane, 64 KB total. Real plane ldsR[l]={Pr,Qr}, imag plane
// ldsI[l]={Pi,Qi} -> every b64 exchange access moves exactly one v2f register
// pair, ZERO repack movs; ex2's contiguous b128 reads give {v[m],v[m+1]}
// directly. XOR swizzle per plane unchanged from v5:
//   phys(l) = l ^ (((l>>4)&7)<<1)   (conflict-free for all 4 exchange
//   patterns; bit0 untouched -> b128 pairs stay adjacent+aligned).
//
// launch_bounds(NT,2): 256-VGPR budget -> no spill (v4 lesson). 2 blocks/CU
// by LDS; v6 showed this occupancy is survivable — the win here is fewer
// instructions, not more waves.

typedef float v2f __attribute__((ext_vector_type(2)));
typedef float v4f __attribute__((ext_vector_type(4)));

// 16-point DFT on packed columns: v[k] = sum_j v[j] * w16^{jk}
// (INV=true: conjugated; unnormalized). Natural order in/out.
template<bool INV>
__device__ __forceinline__ void dft16(v2f* vr, v2f* vi) {
    constexpr float C1 = 0.9238795325112867f;   // cos(pi/8)
    constexpr float S1 = 0.3826834323650898f;   // sin(pi/8)
    constexpr float HF = 0.7071067811865476f;
    const float WR[10] = {1.f,  C1,  HF,  S1, 0.f, 0.f, -HF, 0.f, 0.f, -C1};
    const float WI[10] = {0.f, -S1, -HF, -C1, -1.f, 0.f, -HF, 0.f, 0.f,  S1};

    v2f ar[16], ai[16];
    #pragma unroll
    for (int jl = 0; jl < 4; ++jl) {
        v2f x0r = vr[jl],      x0i = vi[jl];
        v2f x1r = vr[jl + 4],  x1i = vi[jl + 4];
        v2f x2r = vr[jl + 8],  x2i = vi[jl + 8];
        v2f x3r = vr[jl + 12], x3i = vi[jl + 12];
        v2f t0r = x0r + x2r, t0i = x0i + x2i;
        v2f t1r = x0r - x2r, t1i = x0i - x2i;
        v2f t2r = x1r + x3r, t2i = x1i + x3i;
        v2f t3r = x1r - x3r, t3i = x1i - x3i;
        ar[jl]     = t0r + t2r;  ai[jl]     = t0i + t2i;
        ar[jl + 8] = t0r - t2r;  ai[jl + 8] = t0i - t2i;
        if (!INV) {
            ar[jl + 4]  = t1r + t3i;  ai[jl + 4]  = t1i - t3r;  // t1 - i*t3
            ar[jl + 12] = t1r - t3i;  ai[jl + 12] = t1i + t3r;  // t1 + i*t3
        } else {
            ar[jl + 4]  = t1r - t3i;  ai[jl + 4]  = t1i + t3r;
            ar[jl + 12] = t1r + t3i;  ai[jl + 12] = t1i - t3r;
        }
    }
    #pragma unroll
    for (int k4 = 1; k4 < 4; ++k4) {
        #pragma unroll
        for (int jl = 1; jl < 4; ++jl) {
            const int e = jl * k4;
            const float wr = WR[e];
            const float wi = INV ? -WI[e] : WI[e];
            const int id = jl + 4 * k4;
            v2f xr = ar[id], xi = ai[id];
            ar[id] = xr * wr - xi * wi;
            ai[id] = xr * wi + xi * wr;
        }
    }
    #pragma unroll
    for (int k4 = 0; k4 < 4; ++k4) {
        v2f x0r = ar[4*k4 + 0], x0i = ai[4*k4 + 0];
        v2f x1r = ar[4*k4 + 1], x1i = ai[4*k4 + 1];
        v2f x2r = ar[4*k4 + 2], x2i = ai[4*k4 + 2];
        v2f x3r = ar[4*k4 + 3], x3i = ai[4*k4 + 3];
        v2f t0r = x0r + x2r, t0i = x0i + x2i;
        v2f t1r = x0r - x2r, t1i = x0i - x2i;
        v2f t2r = x1r + x3r, t2i = x1i + x3i;
        v2f t3r = x1r - x3r, t3i = x1i - x3i;
        vr[k4]     = t0r + t2r;  vi[k4]     = t0i + t2i;
        vr[k4 + 8] = t0r - t2r;  vi[k4 + 8] = t0i - t2i;
        if (!INV) {
            vr[k4 + 4]  = t1r + t3i;  vi[k4 + 4]  = t1i - t3r;
            vr[k4 + 12] = t1r - t3i;  vi[k4 + 12] = t1i + t3r;
        } else {
            vr[k4 + 4]  = t1r - t3i;  vi[k4 + 4]  = t1i + t3r;
            vr[k4 + 12] = t1r + t3i;  vi[k4 + 12] = t1i - t3r;
        }
    }
}

// v[e] *= (wr,wi)^e for e=1..15. Power chain in scalars (shared by both
// columns), application packed. Two chains stepping w^2 halve serial latency.
__device__ __forceinline__ void apply_tw(v2f* vr, v2f* vi, float wr, float wi) {
    const float w2r = wr * wr - wi * wi;
    const float w2i = 2.0f * wr * wi;
    float aor = wr,  aoi = wi;    // odd powers
    float aer = w2r, aei = w2i;   // even powers
    #pragma unroll
    for (int e = 1; e < 16; e += 2) {
        { v2f xr = vr[e], xi = vi[e];
          vr[e] = xr * aor - xi * aoi;
          vi[e] = xr * aoi + xi * aor; }
        if (e + 1 < 16) {
            v2f xr = vr[e + 1], xi = vi[e + 1];
            vr[e + 1] = xr * aer - xi * aei;
            vi[e + 1] = xr * aei + xi * aer;
        }
        if (e + 2 < 16) {
            float nr = aor * w2r - aoi * w2i, ni = aor * w2i + aoi * w2r;
            aor = nr; aoi = ni;
            nr = aer * w2r - aei * w2i; ni = aer * w2i + aei * w2r;
            aer = nr; aei = ni;
        }
    }
}

__device__ __forceinline__ void cmul(v2f& r, v2f& i, float hr, float hi) {
    v2f xr = r, xi = i;
    r = xr * hr - xi * hi;
    i = xr * hi + xi * hr;
}

__global__ __launch_bounds__(NT, 2) void spectral_circulant_r16v7(
    const float* __restrict__ x,
    const float* __restrict__ w_real,
    const float* __restrict__ w_imag,
    const float* __restrict__ bias_p,
    float* __restrict__ out)
{
    __shared__ __align__(16) v2f ldsR[4096];   // {Pr,Qr} plane, 32 KB
    __shared__ __align__(16) v2f ldsI[4096];   // {Pi,Qi} plane, 32 KB

    const int t   = threadIdx.x;
    const int blk = blockIdx.x;

    v2f vr[16], vi[16];

    // ---- load four rows: P = r0 + i*r1, Q = r2 + i*r3 (packed {P,Q}) ----
    const float* __restrict__ xa = x + (size_t)(4 * blk) * 4096;
    #pragma unroll
    for (int j = 0; j < 16; ++j) {
        const int o = (j << 8) + t;
        vr[j] = (v2f){xa[o],        xa[o + 8192]};
        vi[j] = (v2f){xa[o + 4096], xa[o + 12288]};
    }

    // ---- stage A: DFT16 over j -> digit a; twiddle W4096^{t*a} ----
    dft16<false>(vr, vi);
    float sA, cA;
    __sincosf((float)t * -1.5339807878856412e-3f, &sA, &cA);  // -2pi/4096
    apply_tw(vr, vi, cA, sA);

    // ---- exchange 1 write: l = 256a + t; phys = 256a + tswz (b64 x2 planes) ----
    {
        const int tswz = t ^ ((t >> 3) & 0xE);   // t ^ (((t>>4)&7)<<1)
        #pragma unroll
        for (int a = 0; a < 16; ++a) {
            ldsR[(a << 8) + tswz] = vr[a];
            ldsI[(a << 8) + tswz] = vi[a];
        }
    }
    __syncthreads();

    const int ax = t >> 4;               // upper digit this thread owns from here on
    const int m2 = t & 15;               // lower digit

    // 8 swizzled column bases: phys(256ax + 16q + m2) = swzbase[q&7] + 16q.
    int swzbase[8];
    #pragma unroll
    for (int c = 0; c < 8; ++c)
        swzbase[c] = (ax << 8) + (m2 ^ (c << 1));

    // ---- exchange 1 read: l = 256ax + 16q + m2 ----
    #pragma unroll
    for (int q = 0; q < 16; ++q) {
        vr[q] = ldsR[swzbase[q & 7] + (q << 4)];
        vi[q] = ldsI[swzbase[q & 7] + (q << 4)];
    }

    // ---- stage B: DFT16 over q -> digit b; twiddle W256^{m2*b} ----
    dft16<false>(vr, vi);
    float sB, cB;
    __sincosf((float)m2 * -2.454369260617026e-2f, &sB, &cB);  // -2pi/256
    apply_tw(vr, vi, cB, sB);

    // ---- exchange 2 write: l = 256ax + 16b + m2 — wave-local (16-lane groups) ----
    #pragma unroll
    for (int b = 0; b < 16; ++b) {
        ldsR[swzbase[b & 7] + (b << 4)] = vr[b];
        ldsI[swzbase[b & 7] + (b << 4)] = vi[b];
    }
    __builtin_amdgcn_wave_barrier();

    // ---- exchange 2 read: 16 contiguous at l0 = 256ax + 16*m2;
    // phys = l0 + (m ^ c2), c2 even -> slot pairs adjacent+16B-aligned (b128) ----
    const int c2 = (m2 & 7) << 1;
    const int l0 = (ax << 8) + (m2 << 4);
    #pragma unroll
    for (int m = 0; m < 16; m += 2) {
        v4f r4 = *(const v4f*)&ldsR[l0 + (m ^ c2)];
        v4f i4 = *(const v4f*)&ldsI[l0 + (m ^ c2)];
        vr[m] = r4.xy;  vr[m + 1] = r4.zw;
        vi[m] = i4.xy;  vi[m + 1] = i4.zw;
    }

    // ---- stage C: DFT16 over m -> digit r3; freq k = 256*r3 + 16*m2 + ax ----
    dft16<false>(vr, vi);

    // ---- pointwise H[k]/N — H loads shared by both packed columns ----
    {
        const int c = (m2 << 4) | ax;            // in [0,255]
        const float sc = 1.0f / 4096.0f;
        #pragma unroll
        for (int r3 = 0; r3 < 4; ++r3) {         // k < 1024: active
            const int k = (r3 << 8) + c;
            cmul(vr[r3], vi[r3], w_real[k] * sc, w_imag[k] * sc);
        }
        #pragma unroll
        for (int r3 = 4; r3 < 12; ++r3) {        // truncated band
            vr[r3] = (v2f){0.0f, 0.0f};
            vi[r3] = (v2f){0.0f, 0.0f};
        }
        {                                        // r3=12: k=3072+c, active iff c>0
            const int idx = 1024 - c;
            const float mm = (c > 0) ? sc : 0.0f;
            cmul(vr[12], vi[12], w_real[idx] * mm, -w_imag[idx] * mm);
        }
        #pragma unroll
        for (int r3 = 13; r3 < 16; ++r3) {       // k > 3072: conj mirror
            const int idx = ((16 - r3) << 8) - c;
            cmul(vr[r3], vi[r3], w_real[idx] * sc, -w_imag[idx] * sc);
        }
    }

    // ================= inverse: exact adjoint, reverse order =================

    // ---- C^H ----
    dft16<true>(vr, vi);

    // ---- exchange 2 reverse write (b128 x2 planes) ----
    #pragma unroll
    for (int m = 0; m < 16; m += 2) {
        v4f r4, i4;
        r4.xy = vr[m];  r4.zw = vr[m + 1];
        i4.xy = vi[m];  i4.zw = vi[m + 1];
        *(v4f*)&ldsR[l0 + (m ^ c2)] = r4;
        *(v4f*)&ldsI[l0 + (m ^ c2)] = i4;
    }
    __builtin_amdgcn_wave_barrier();

    // ---- exchange 2 reverse read: l = 256ax + 16b + m2 over b ----
    #pragma unroll
    for (int b = 0; b < 16; ++b) {
        vr[b] = ldsR[swzbase[b & 7] + (b << 4)];
        vi[b] = ldsI[swzbase[b & 7] + (b << 4)];
    }

    // ---- B^H ----
    apply_tw(vr, vi, cB, -sB);
    dft16<true>(vr, vi);

    // ---- exchange 1 reverse write ----
    #pragma unroll
    for (int q = 0; q < 16; ++q) {
        ldsR[swzbase[q & 7] + (q << 4)] = vr[q];
        ldsI[swzbase[q & 7] + (q << 4)] = vi[q];
    }
    __syncthreads();

    // ---- exchange 1 reverse read: l = 256a + t ----
    {
        const int tswz = t ^ ((t >> 3) & 0xE);
        #pragma unroll
        for (int a = 0; a < 16; ++a) {
            vr[a] = ldsR[(a << 8) + tswz];
            vi[a] = ldsI[(a << 8) + tswz];
        }
    }

    // ---- A^H ----
    apply_tw(vr, vi, cA, -sA);
    dft16<true>(vr, vi);

    // ---- store (nontemporal: streamed output) ----
    const float bv = bias_p[0];
    float* __restrict__ oa = out + (size_t)(4 * blk) * 4096;
    #pragma unroll
    for (int j = 0; j < 16; ++j) {
        const int o = (j << 8) + t;
        __builtin_nontemporal_store(vr[j].x + bv, &oa[o]);
        __builtin_nontemporal_store(vi[j].x + bv, &oa[o + 4096]);
        __builtin_nontemporal_store(vr[j].y + bv, &oa[o + 8192]);
        __builtin_nontemporal_store(vi[j].y + bv, &oa[o + 12288]);
    }
}

extern "C" void kernel_launch(void* const* d_in, const int* in_sizes, int n_in,
                              void* d_out, int out_size, void* d_ws, size_t ws_size,
                              hipStream_t stream) {
    (void)in_sizes; (void)n_in; (void)d_ws; (void)ws_size; (void)out_size;
    const float* x      = (const float*)d_in[0];   // (8192, 4096) f32
    const float* w_real = (const float*)d_in[1];   // (2049,) f32
    const float* w_imag = (const float*)d_in[2];   // (2049,) f32
    const float* bias   = (const float*)d_in[3];   // scalar f32
    float* out = (float*)d_out;                    // (8192, 4096) f32

    spectral_circulant_r16v7<<<8192 / 4, NT, 0, stream>>>(x, w_real, w_imag, bias, out);
}